// Round 1
// baseline (974.274 us; speedup 1.0000x reference)
//
#include <hip/hip_runtime.h>
#include <hip/hip_bf16.h>

typedef __attribute__((ext_vector_type(8))) short short8;
typedef __attribute__((ext_vector_type(4))) float f32x4;

#define AS1 __attribute__((address_space(1)))
#define AS3 __attribute__((address_space(3)))

__device__ __forceinline__ void gld16(const short* g, short* l) {
  __builtin_amdgcn_global_load_lds((const AS1 void*)g, (AS3 void*)l, 16, 0, 0);
}

__device__ __forceinline__ float bf2f(short x) {
  return __uint_as_float(((unsigned)(unsigned short)x) << 16);
}
__device__ __forceinline__ short f2bf(float f) {
  unsigned u = __float_as_uint(f);
  return (short)((u + 0x7fffu + ((u >> 16) & 1u)) >> 16);  // RNE
}

// ---------------- cast fp32 -> bf16, 8 elems/thread ----------------
__global__ void cast_f32_bf16(const float* __restrict__ src, short* __restrict__ dst, int n8) {
  int stride = gridDim.x * blockDim.x;
  for (int i = blockIdx.x * blockDim.x + threadIdx.x; i < n8; i += stride) {
    const float4* s = (const float4*)(src + (size_t)i * 8);
    float4 a = s[0], b = s[1];
    short8 o;
    o[0] = f2bf(a.x); o[1] = f2bf(a.y); o[2] = f2bf(a.z); o[3] = f2bf(a.w);
    o[4] = f2bf(b.x); o[5] = f2bf(b.y); o[6] = f2bf(b.z); o[7] = f2bf(b.w);
    *(short8*)(dst + (size_t)i * 8) = o;
  }
}

// ---------------- bf16 GEMM, C[M,N] = A[M,K] * B[N,K]^T + bias ----------------
// m97 structure: 128x128 tile, BK=32, 4 waves (2x2), 4x4 16x16x32 frags/wave,
// global_load_lds width=16, linear LDS.
template<int OUT_BF16>
__global__ __launch_bounds__(256, 2) void gemm_bt(
    const short* __restrict__ A, const short* __restrict__ Bm,
    const float* __restrict__ bias, void* __restrict__ C,
    int M, int N, int Kd, int NB)
{
  __shared__ short As[128 * 32];
  __shared__ short Bs[128 * 32];
  int tid = threadIdx.x;
  int wave = tid >> 6, lane = tid & 63;
  int mblk = blockIdx.x / NB, nblk = blockIdx.x % NB;
  size_t arow0 = (size_t)mblk * 128;
  size_t brow0 = (size_t)nblk * 128;
  int wm = wave >> 1, wn = wave & 1;
  int lr = lane & 15, lk = (lane >> 4) * 8;

  // staging: chunk f (16B) -> LDS byte f*16; row=f>>2, seg=f&3 in global
  int f0 = wave * 128 + lane;
  int f1 = f0 + 64;
  const short* ga0 = A + (arow0 + (size_t)(f0 >> 2)) * Kd + (f0 & 3) * 8;
  const short* ga1 = A + (arow0 + (size_t)(f1 >> 2)) * Kd + (f1 & 3) * 8;
  const short* gb0 = Bm + (brow0 + (size_t)(f0 >> 2)) * Kd + (f0 & 3) * 8;
  const short* gb1 = Bm + (brow0 + (size_t)(f1 >> 2)) * Kd + (f1 & 3) * 8;
  short* la0 = &As[wave * 1024];   // wave-uniform LDS bases
  short* la1 = la0 + 512;
  short* lb0 = &Bs[wave * 1024];
  short* lb1 = lb0 + 512;

  f32x4 acc[4][4];
  #pragma unroll
  for (int i = 0; i < 4; ++i)
    #pragma unroll
    for (int j = 0; j < 4; ++j) {
      acc[i][j][0] = 0.f; acc[i][j][1] = 0.f; acc[i][j][2] = 0.f; acc[i][j][3] = 0.f;
    }

  int abase = (wm * 64 + lr) * 32 + lk;
  int bbase = (wn * 64 + lr) * 32 + lk;

  for (int k0 = 0; k0 < Kd; k0 += 32) {
    gld16(ga0 + k0, la0);
    gld16(ga1 + k0, la1);
    gld16(gb0 + k0, lb0);
    gld16(gb1 + k0, lb1);
    __syncthreads();   // compiler emits vmcnt(0) drain before barrier
    short8 af[4], bfr[4];
    #pragma unroll
    for (int i = 0; i < 4; ++i) {
      af[i]  = *(const short8*)&As[abase + i * 512];
      bfr[i] = *(const short8*)&Bs[bbase + i * 512];
    }
    #pragma unroll
    for (int i = 0; i < 4; ++i)
      #pragma unroll
      for (int j = 0; j < 4; ++j)
        acc[i][j] = __builtin_amdgcn_mfma_f32_16x16x32_bf16(af[i], bfr[j], acc[i][j], 0, 0, 0);
    __syncthreads();
  }

  // C/D layout: col = lane&15, row = (lane>>4)*4 + reg  [m89/m91 verified]
  int r0 = (lane >> 4) * 4;
  #pragma unroll
  for (int i = 0; i < 4; ++i) {
    size_t grow0 = arow0 + wm * 64 + i * 16 + r0;
    #pragma unroll
    for (int j = 0; j < 4; ++j) {
      size_t gcol = brow0 + wn * 64 + j * 16 + lr;
      float bv = bias[gcol];
      #pragma unroll
      for (int r = 0; r < 4; ++r) {
        float v = acc[i][j][r] + bv;
        size_t off = (grow0 + r) * (size_t)N + gcol;
        if (OUT_BF16) ((short*)C)[off] = f2bf(v);
        else          ((float*)C)[off] = v;
      }
    }
  }
}

// ---------------- local 7x7 attention ----------------
// 8x16 query tile / 128 threads (1 query per thread), K then V staged in the
// same LDS buffer (two passes). XOR chunk swizzle kills the stride-128B bank
// conflict on the per-neighbor vector reads. Scores live in LDS (runtime o
// index would spill to scratch otherwise).
#define ATH 8
#define ATW 16
#define HHH 14
#define HWW 22

__global__ __launch_bounds__(128, 2) void attn_kernel(
    const short* __restrict__ qkv, const float* __restrict__ rel_bias,
    short* __restrict__ attn_out)
{
  __shared__ short kv[HHH * HWW * 64];   // 39424 B
  __shared__ float s_lds[49 * 128];      // 25088 B -> total 64512 B
  int tid = threadIdx.x;
  int tile = blockIdx.x;                 // 0..27 : 7 h-tiles x 4 w-tiles
  int ht = tile >> 2, wt = tile & 3;
  int bh = blockIdx.y;                   // b*12 + head
  int head = bh % 12, b = bh / 12;
  int h0 = ht * ATH, w0 = wt * ATW;
  int th = tid >> 4, tw = tid & 15;
  int h = h0 + th, w = w0 + tw;
  bool qv = (w < 56);

  float q[64];
  if (qv) {
    const short* qp = qkv + ((size_t)((b * 56 + h) * 56 + w)) * 2304 + head * 64;
    #pragma unroll
    for (int c = 0; c < 8; ++c) {
      short8 v = *(const short8*)(qp + c * 8);
      #pragma unroll
      for (int j = 0; j < 8; ++j) q[c * 8 + j] = bf2f(v[j]);
    }
  } else {
    #pragma unroll
    for (int d = 0; d < 64; ++d) q[d] = 0.0f;
  }

  auto stage = [&](int tensor) {
    #pragma unroll
    for (int it = 0; it < 20; ++it) {
      int idx = it * 128 + tid;
      if (idx < HHH * HWW * 8) {
        int vec = idx >> 3, c = idx & 7;
        int hh = vec / HWW, ww = vec - hh * HWW;
        int gh = h0 - 3 + hh, gw = w0 - 3 + ww;
        short8 val;
        if (gh >= 0 && gh < 56 && gw >= 0 && gw < 56) {
          val = *(const short8*)(qkv + ((size_t)((b * 56 + gh) * 56 + gw)) * 2304
                                 + tensor * 768 + head * 64 + c * 8);
        } else {
          #pragma unroll
          for (int j = 0; j < 8; ++j) val[j] = 0;   // zero-fill OOB (masked anyway)
        }
        *(short8*)&kv[(vec * 8 + (c ^ (vec & 7))) * 8] = val;
      }
    }
  };

  stage(1);            // K
  __syncthreads();

  float mx = -1e30f;
  #pragma unroll 1
  for (int o = 0; o < 49; ++o) {
    int di = o / 7, dj = o - di * 7;
    int nh = h + di - 3, nw = w + dj - 3;
    bool nv = qv && ((unsigned)nh < 56u) && ((unsigned)nw < 56u);
    int vec = (th + di) * HWW + (tw + dj);
    float a0 = 0.f, a1 = 0.f, a2 = 0.f, a3 = 0.f;
    #pragma unroll
    for (int c = 0; c < 8; ++c) {
      short8 kk = *(const short8*)&kv[(vec * 8 + (c ^ (vec & 7))) * 8];
      a0 = fmaf(q[c*8+0], bf2f(kk[0]), a0);
      a1 = fmaf(q[c*8+1], bf2f(kk[1]), a1);
      a2 = fmaf(q[c*8+2], bf2f(kk[2]), a2);
      a3 = fmaf(q[c*8+3], bf2f(kk[3]), a3);
      a0 = fmaf(q[c*8+4], bf2f(kk[4]), a0);
      a1 = fmaf(q[c*8+5], bf2f(kk[5]), a1);
      a2 = fmaf(q[c*8+6], bf2f(kk[6]), a2);
      a3 = fmaf(q[c*8+7], bf2f(kk[7]), a3);
    }
    float sc = (a0 + a1 + a2 + a3) * 0.125f + rel_bias[head * 49 + o];
    sc = nv ? sc : -1e30f;   // select discards any garbage
    s_lds[o * 128 + tid] = sc;
    mx = fmaxf(mx, sc);
  }

  float sum = 0.0f;
  #pragma unroll 1
  for (int o = 0; o < 49; ++o) {
    float e = __expf(s_lds[o * 128 + tid] - mx);
    s_lds[o * 128 + tid] = e;
    sum += e;
  }
  float inv = 1.0f / sum;    // center neighbor always valid -> sum >= 1 for qv

  __syncthreads();           // everyone done reading K
  stage(2);                  // V into the same buffer
  __syncthreads();

  float outv[64];
  #pragma unroll
  for (int d = 0; d < 64; ++d) outv[d] = 0.0f;
  #pragma unroll 1
  for (int o = 0; o < 49; ++o) {
    float wgt = s_lds[o * 128 + tid];   // 0 for invalid neighbors
    int di = o / 7, dj = o - di * 7;
    int vec = (th + di) * HWW + (tw + dj);
    #pragma unroll
    for (int c = 0; c < 8; ++c) {
      short8 vv = *(const short8*)&kv[(vec * 8 + (c ^ (vec & 7))) * 8];
      #pragma unroll
      for (int j = 0; j < 8; ++j)
        outv[c * 8 + j] = fmaf(wgt, bf2f(vv[j]), outv[c * 8 + j]);
    }
  }

  if (qv) {
    short* op = attn_out + ((size_t)((b * 56 + h) * 56 + w)) * 768 + head * 64;
    #pragma unroll
    for (int c = 0; c < 8; ++c) {
      short8 ov;
      #pragma unroll
      for (int j = 0; j < 8; ++j) ov[j] = f2bf(outv[c * 8 + j] * inv);
      *(short8*)(op + c * 8) = ov;
    }
  }
}

// ---------------- launch ----------------
extern "C" void kernel_launch(void* const* d_in, const int* in_sizes, int n_in,
                              void* d_out, int out_size, void* d_ws, size_t ws_size,
                              hipStream_t stream)
{
  const float* x      = (const float*)d_in[0];
  const float* qkv_w  = (const float*)d_in[1];
  const float* qkv_b  = (const float*)d_in[2];
  const float* rel_b  = (const float*)d_in[3];
  const float* proj_w = (const float*)d_in[4];
  const float* proj_b = (const float*)d_in[5];

  char* ws = (char*)d_ws;
  // ws layout (bytes, 256-aligned):
  //   [0, 77070336)            x_bf16, later reused as attn_out_bf16
  //   [77070336, 80609280)     qkv_w bf16
  //   [80609280, 81788928)     proj_w bf16
  //   [81788928, 312999936)    qkv bf16 [50176 x 2304]
  short* x_bf    = (short*)(ws);
  short* attn_bf = (short*)(ws);                 // reuse (x dead after qkv GEMM)
  short* qw_bf   = (short*)(ws + 77070336);
  short* pw_bf   = (short*)(ws + 80609280);
  short* qkv_bf  = (short*)(ws + 81788928);

  cast_f32_bf16<<<2048, 256, 0, stream>>>(x, x_bf, 38535168 / 8);
  cast_f32_bf16<<<864, 256, 0, stream>>>(qkv_w, qw_bf, 1769472 / 8);
  cast_f32_bf16<<<288, 256, 0, stream>>>(proj_w, pw_bf, 589824 / 8);

  // qkv = x @ qkv_w^T + qkv_b   (M=50176, N=2304, K=768)
  gemm_bt<1><<<392 * 18, 256, 0, stream>>>(x_bf, qw_bf, qkv_b, (void*)qkv_bf,
                                           50176, 2304, 768, 18);

  // local attention -> attn_bf [50176 x 768]
  attn_kernel<<<dim3(28, 192), 128, 0, stream>>>(qkv_bf, rel_b, attn_bf);

  // out = attn @ proj_w^T + proj_b  (M=50176, N=768, K=768), fp32 out
  gemm_bt<0><<<392 * 6, 256, 0, stream>>>(attn_bf, pw_bf, proj_b, d_out,
                                          50176, 768, 768, 6);
}

// Round 2
// 584.764 us; speedup vs baseline: 1.6661x; 1.6661x over previous
//
#include <hip/hip_runtime.h>
#include <hip/hip_bf16.h>

typedef __attribute__((ext_vector_type(8))) short short8;
typedef __attribute__((ext_vector_type(4))) short s16x4;
typedef __attribute__((ext_vector_type(4))) float f32x4;

#define AS1 __attribute__((address_space(1)))
#define AS3 __attribute__((address_space(3)))

__device__ __forceinline__ void gld16(const short* g, short* l) {
  __builtin_amdgcn_global_load_lds((const AS1 void*)g, (AS3 void*)l, 16, 0, 0);
}

__device__ __forceinline__ float bf2f(short x) {
  return __uint_as_float(((unsigned)(unsigned short)x) << 16);
}
__device__ __forceinline__ short f2bf(float f) {
  unsigned u = __float_as_uint(f);
  return (short)((u + 0x7fffu + ((u >> 16) & 1u)) >> 16);  // RNE
}

// ---------------- cast fp32 -> bf16, 8 elems/thread ----------------
__global__ void cast_f32_bf16(const float* __restrict__ src, short* __restrict__ dst, int n8) {
  int stride = gridDim.x * blockDim.x;
  for (int i = blockIdx.x * blockDim.x + threadIdx.x; i < n8; i += stride) {
    const float4* s = (const float4*)(src + (size_t)i * 8);
    float4 a = s[0], b = s[1];
    short8 o;
    o[0] = f2bf(a.x); o[1] = f2bf(a.y); o[2] = f2bf(a.z); o[3] = f2bf(a.w);
    o[4] = f2bf(b.x); o[5] = f2bf(b.y); o[6] = f2bf(b.z); o[7] = f2bf(b.w);
    *(short8*)(dst + (size_t)i * 8) = o;
  }
}

// ---------------- bf16 GEMM, C[M,N] = A[M,K] * B[N,K]^T + bias ----------------
template<int OUT_BF16>
__global__ __launch_bounds__(256, 2) void gemm_bt(
    const short* __restrict__ A, const short* __restrict__ Bm,
    const float* __restrict__ bias, void* __restrict__ C,
    int M, int N, int Kd, int NB)
{
  __shared__ short As[128 * 32];
  __shared__ short Bs[128 * 32];
  int tid = threadIdx.x;
  int wave = tid >> 6, lane = tid & 63;
  int mblk = blockIdx.x / NB, nblk = blockIdx.x % NB;
  size_t arow0 = (size_t)mblk * 128;
  size_t brow0 = (size_t)nblk * 128;
  int wm = wave >> 1, wn = wave & 1;
  int lr = lane & 15, lk = (lane >> 4) * 8;

  int f0 = wave * 128 + lane;
  int f1 = f0 + 64;
  const short* ga0 = A + (arow0 + (size_t)(f0 >> 2)) * Kd + (f0 & 3) * 8;
  const short* ga1 = A + (arow0 + (size_t)(f1 >> 2)) * Kd + (f1 & 3) * 8;
  const short* gb0 = Bm + (brow0 + (size_t)(f0 >> 2)) * Kd + (f0 & 3) * 8;
  const short* gb1 = Bm + (brow0 + (size_t)(f1 >> 2)) * Kd + (f1 & 3) * 8;
  short* la0 = &As[wave * 1024];
  short* la1 = la0 + 512;
  short* lb0 = &Bs[wave * 1024];
  short* lb1 = lb0 + 512;

  f32x4 acc[4][4];
  #pragma unroll
  for (int i = 0; i < 4; ++i)
    #pragma unroll
    for (int j = 0; j < 4; ++j) {
      acc[i][j][0] = 0.f; acc[i][j][1] = 0.f; acc[i][j][2] = 0.f; acc[i][j][3] = 0.f;
    }

  int abase = (wm * 64 + lr) * 32 + lk;
  int bbase = (wn * 64 + lr) * 32 + lk;

  for (int k0 = 0; k0 < Kd; k0 += 32) {
    gld16(ga0 + k0, la0);
    gld16(ga1 + k0, la1);
    gld16(gb0 + k0, lb0);
    gld16(gb1 + k0, lb1);
    __syncthreads();
    short8 af[4], bfr[4];
    #pragma unroll
    for (int i = 0; i < 4; ++i) {
      af[i]  = *(const short8*)&As[abase + i * 512];
      bfr[i] = *(const short8*)&Bs[bbase + i * 512];
    }
    #pragma unroll
    for (int i = 0; i < 4; ++i)
      #pragma unroll
      for (int j = 0; j < 4; ++j)
        acc[i][j] = __builtin_amdgcn_mfma_f32_16x16x32_bf16(af[i], bfr[j], acc[i][j], 0, 0, 0);
    __syncthreads();
  }

  int r0 = (lane >> 4) * 4;
  #pragma unroll
  for (int i = 0; i < 4; ++i) {
    size_t grow0 = arow0 + wm * 64 + i * 16 + r0;
    #pragma unroll
    for (int j = 0; j < 4; ++j) {
      size_t gcol = brow0 + wn * 64 + j * 16 + lr;
      float bv = bias[gcol];
      #pragma unroll
      for (int r = 0; r < 4; ++r) {
        float v = acc[i][j][r] + bv;
        size_t off = (grow0 + r) * (size_t)N + gcol;
        if (OUT_BF16) ((short*)C)[off] = f2bf(v);
        else          ((float*)C)[off] = v;
      }
    }
  }
}

// ---------------- MFMA local 7x7 attention ----------------
// Block: 4x16 query tile (4 waves, 1 wave = 1 query row of 16).
// K halo [232 vecs][64 d] in LDS w/ chunk-XOR swizzle; QK^T via mfma with K as
// A-operand -> C[key,q]: lane holds 40 scores of one query. Softmax in-register
// (2 shfl_xor). P -> LDS [16][168] per wave, V restaged TRANSPOSED [d][vec]
// into the same buffer for the PV B-operand.
#define HALO_V 232
#define PROW 168

__global__ __launch_bounds__(256, 3) void attn_mfma(
    const short* __restrict__ qkv, const float* __restrict__ rel_bias,
    short* __restrict__ attn_out)
{
  __shared__ __align__(16) short kvbuf[HALO_V * 64];     // 29696 B (K, then V^T)
  __shared__ __align__(16) short pbuf[4 * 16 * PROW];    // 21504 B
  __shared__ float sbias[49];

  const int tid = threadIdx.x;
  const int wave = tid >> 6, lane = tid & 63;
  const int ht = blockIdx.x >> 2, wt = blockIdx.x & 3;
  const int head = blockIdx.y % 12, b = blockIdx.y / 12;
  const int r0 = ht * 4, c0 = wt * 16;
  const int grp = lane >> 4;           // 0..3
  const int q   = lane & 15;           // query col within tile / d within tile
  const int grp4 = grp * 4, grp8 = grp * 8;
  const int Sw = (22 * wave) & ~7;     // wave key-window start (8-aligned)

  if (tid < 49) sbias[tid] = rel_bias[head * 49 + tid];

  // ---- stage K halo (chunk-XOR swizzled) ----
  #pragma unroll
  for (int it = 0; it < 8; ++it) {
    int idx = it * 256 + tid;
    if (idx < HALO_V * 8) {
      int vec = idx >> 3, c = idx & 7;
      int hr = vec / 22, hc = vec - hr * 22;
      int gh = r0 - 3 + hr, gw = c0 - 3 + hc;
      short8 val = {};
      if (vec < 220 && (unsigned)gh < 56u && (unsigned)gw < 56u)
        val = *(const short8*)(qkv + ((size_t)((b * 56 + gh) * 56 + gw)) * 2304
                               + 768 + head * 64 + c * 8);
      *(short8*)&kvbuf[vec * 64 + ((c ^ (vec & 7))) * 8] = val;
    }
  }

  // ---- Q fragments from global (B-operand: row q, dims grp8..grp8+7 / +32) ----
  const int qrow = r0 + wave;
  const int qcol = min(c0 + q, 55);
  const short* qp = qkv + ((size_t)((b * 56 + qrow) * 56 + qcol)) * 2304 + head * 64;
  short8 qf0 = *(const short8*)(qp + grp8);
  short8 qf1 = *(const short8*)(qp + 32 + grp8);

  __syncthreads();

  // ---- QK^T: C[key, q], 10 key-tiles x (K=64 -> 2 mfma) ----
  f32x4 accs[10];
  #pragma unroll
  for (int kt = 0; kt < 10; ++kt) {
    accs[kt][0] = 0.f; accs[kt][1] = 0.f; accs[kt][2] = 0.f; accs[kt][3] = 0.f;
  }
  #pragma unroll
  for (int kt = 0; kt < 10; ++kt) {
    int vec = Sw + kt * 16 + q;
    int sw = vec & 7;
    short8 k0 = *(const short8*)&kvbuf[vec * 64 + ((grp ^ sw)) * 8];
    short8 k1 = *(const short8*)&kvbuf[vec * 64 + (((grp + 4) ^ sw)) * 8];
    accs[kt] = __builtin_amdgcn_mfma_f32_16x16x32_bf16(k0, qf0, accs[kt], 0, 0, 0);
    accs[kt] = __builtin_amdgcn_mfma_f32_16x16x32_bf16(k1, qf1, accs[kt], 0, 0, 0);
  }

  __syncthreads();   // all waves done reading K

  // ---- restage V TRANSPOSED: V_t[d=0..63][vec], stride HALO_V ----
  if (tid < HALO_V) {
    int vec = tid;
    int hr = vec / 22, hc = vec - hr * 22;
    int gh = r0 - 3 + hr, gw = c0 - 3 + hc;
    bool v = (vec < 220) && ((unsigned)gh < 56u) && ((unsigned)gw < 56u);
    int ghc = v ? gh : 0, gwc = v ? gw : 0;
    const short* vp = qkv + ((size_t)((b * 56 + ghc) * 56 + gwc)) * 2304
                      + 1536 + head * 64;
    #pragma unroll
    for (int c = 0; c < 8; ++c) {
      short8 val = {};
      if (v) val = *(const short8*)(vp + c * 8);
      #pragma unroll
      for (int j = 0; j < 8; ++j)
        kvbuf[(c * 8 + j) * HALO_V + vec] = val[j];
    }
  }

  // ---- scores + softmax (register-resident, 40 scores/lane) ----
  float sv[10][4];
  float mx = -1e30f;
  #pragma unroll
  for (int kt = 0; kt < 10; ++kt) {
    #pragma unroll
    for (int r = 0; r < 4; ++r) {
      int i22 = Sw + kt * 16 + grp4 + r;
      int hr = i22 / 22, hc = i22 - hr * 22;
      int dr = hr - wave, dc = hc - q;
      int kh = r0 - 3 + hr, kw = c0 - 3 + hc;
      bool valid = ((unsigned)dr < 7u) && ((unsigned)dc < 7u) &&
                   ((unsigned)kh < 56u) && ((unsigned)kw < 56u);
      int o = valid ? (dr * 7 + dc) : 0;
      float s = accs[kt][r] * 0.125f + sbias[o];
      s = valid ? s : -1e30f;
      sv[kt][r] = s;
      mx = fmaxf(mx, s);
    }
  }
  mx = fmaxf(mx, __shfl_xor(mx, 16));
  mx = fmaxf(mx, __shfl_xor(mx, 32));
  float sum = 0.f;
  #pragma unroll
  for (int kt = 0; kt < 10; ++kt)
    #pragma unroll
    for (int r = 0; r < 4; ++r) {
      float e = __expf(sv[kt][r] - mx);
      sv[kt][r] = e;
      sum += e;
    }
  sum += __shfl_xor(sum, 16);
  sum += __shfl_xor(sum, 32);
  float inv = 1.0f / sum;

  // ---- write P (bf16, 1/sum folded) to pbuf[q][key], row stride PROW ----
  short* pb = pbuf + wave * 16 * PROW;
  #pragma unroll
  for (int kt = 0; kt < 10; ++kt) {
    s16x4 pk;
    #pragma unroll
    for (int r = 0; r < 4; ++r) pk[r] = f2bf(sv[kt][r] * inv);
    *(s16x4*)&pb[q * PROW + kt * 16 + grp4] = pk;
  }

  __syncthreads();   // V_t fully staged

  // ---- PV: out[q, d] = sum_key P[q,key] * V[key,d] ----
  f32x4 acco[4];
  #pragma unroll
  for (int dt = 0; dt < 4; ++dt) {
    acco[dt][0] = 0.f; acco[dt][1] = 0.f; acco[dt][2] = 0.f; acco[dt][3] = 0.f;
  }
  #pragma unroll
  for (int km = 0; km < 5; ++km) {
    short8 pf = *(const short8*)&pb[q * PROW + km * 32 + grp8];
    #pragma unroll
    for (int dt = 0; dt < 4; ++dt) {
      short8 vf = *(const short8*)&kvbuf[(dt * 16 + q) * HALO_V + Sw + km * 32 + grp8];
      acco[dt] = __builtin_amdgcn_mfma_f32_16x16x32_bf16(pf, vf, acco[dt], 0, 0, 0);
    }
  }

  // ---- store: lane holds out[q'=grp4+r][d=dt*16+q] ----
  #pragma unroll
  for (int dt = 0; dt < 4; ++dt) {
    #pragma unroll
    for (int r = 0; r < 4; ++r) {
      int qc = c0 + grp4 + r;
      if (qc < 56) {
        size_t off = ((size_t)((b * 56 + qrow) * 56 + qc)) * 768
                     + head * 64 + dt * 16 + q;
        attn_out[off] = f2bf(acco[dt][r]);
      }
    }
  }
}

// ---------------- launch ----------------
extern "C" void kernel_launch(void* const* d_in, const int* in_sizes, int n_in,
                              void* d_out, int out_size, void* d_ws, size_t ws_size,
                              hipStream_t stream)
{
  const float* x      = (const float*)d_in[0];
  const float* qkv_w  = (const float*)d_in[1];
  const float* qkv_b  = (const float*)d_in[2];
  const float* rel_b  = (const float*)d_in[3];
  const float* proj_w = (const float*)d_in[4];
  const float* proj_b = (const float*)d_in[5];

  char* ws = (char*)d_ws;
  short* x_bf    = (short*)(ws);
  short* attn_bf = (short*)(ws);                 // reuse (x dead after qkv GEMM)
  short* qw_bf   = (short*)(ws + 77070336);
  short* pw_bf   = (short*)(ws + 80609280);
  short* qkv_bf  = (short*)(ws + 81788928);

  cast_f32_bf16<<<2048, 256, 0, stream>>>(x, x_bf, 38535168 / 8);
  cast_f32_bf16<<<864, 256, 0, stream>>>(qkv_w, qw_bf, 1769472 / 8);
  cast_f32_bf16<<<288, 256, 0, stream>>>(proj_w, pw_bf, 589824 / 8);

  // qkv = x @ qkv_w^T + qkv_b   (M=50176, N=2304, K=768)
  gemm_bt<1><<<392 * 18, 256, 0, stream>>>(x_bf, qw_bf, qkv_b, (void*)qkv_bf,
                                           50176, 2304, 768, 18);

  // local attention -> attn_bf [50176 x 768]
  attn_mfma<<<dim3(56, 192), 256, 0, stream>>>(qkv_bf, rel_b, attn_bf);

  // out = attn @ proj_w^T + proj_b  (M=50176, N=768, K=768), fp32 out
  gemm_bt<0><<<392 * 6, 256, 0, stream>>>(attn_bf, pw_bf, proj_b, d_out,
                                          50176, 768, 768, 6);
}

// Round 3
// 530.126 us; speedup vs baseline: 1.8378x; 1.1031x over previous
//
#include <hip/hip_runtime.h>
#include <hip/hip_bf16.h>

typedef __attribute__((ext_vector_type(8))) short short8;
typedef __attribute__((ext_vector_type(4))) short s16x4;
typedef __attribute__((ext_vector_type(4))) float f32x4;

#define AS1 __attribute__((address_space(1)))
#define AS3 __attribute__((address_space(3)))

__device__ __forceinline__ void gld16(const short* g, short* l) {
  __builtin_amdgcn_global_load_lds((const AS1 void*)g, (AS3 void*)l, 16, 0, 0);
}

__device__ __forceinline__ float bf2f(short x) {
  return __uint_as_float(((unsigned)(unsigned short)x) << 16);
}
__device__ __forceinline__ short f2bf(float f) {
  unsigned u = __float_as_uint(f);
  return (short)((u + 0x7fffu + ((u >> 16) & 1u)) >> 16);  // RNE
}

// ---------------- cast fp32 -> bf16, 8 elems/thread ----------------
__global__ void cast_f32_bf16(const float* __restrict__ src, short* __restrict__ dst, int n8) {
  int stride = gridDim.x * blockDim.x;
  for (int i = blockIdx.x * blockDim.x + threadIdx.x; i < n8; i += stride) {
    const float4* s = (const float4*)(src + (size_t)i * 8);
    float4 a = s[0], b = s[1];
    short8 o;
    o[0] = f2bf(a.x); o[1] = f2bf(a.y); o[2] = f2bf(a.z); o[3] = f2bf(a.w);
    o[4] = f2bf(b.x); o[5] = f2bf(b.y); o[6] = f2bf(b.z); o[7] = f2bf(b.w);
    *(short8*)(dst + (size_t)i * 8) = o;
  }
}

// ---------------- bf16 GEMM, C[M,N] = A[M,K] * B[N,K]^T + bias ----------------
// 128x128 tile, BK=64, 4 waves (2x2), T2 XOR-swizzled LDS (inverse-swizzled
// global source for global_load_lds), T1 XCD-chunk + 8-row group raster.
// Requires: M%128==0, N%128==0, K%64==0, grid%8==0.
template<int OUT_BF16>
__global__ __launch_bounds__(256, 2) void gemm_bt(
    const short* __restrict__ A, const short* __restrict__ Bm,
    const float* __restrict__ bias, void* __restrict__ C,
    int M, int N, int Kd, int NB)
{
  __shared__ short As[128 * 64];   // 16 KB, swizzled
  __shared__ short Bs[128 * 64];   // 16 KB, swizzled
  const int tid = threadIdx.x;
  const int wave = tid >> 6, lane = tid & 63;

  // ---- T1 + group raster: XCD-contiguous chunks, 8-mblk super-rows ----
  int nwg = gridDim.x;
  int chunk = nwg >> 3;
  int bid = blockIdx.x;
  int nb2 = (bid & 7) * chunk + (bid >> 3);
  int per = NB << 3;
  int sr = nb2 / per, rem = nb2 - sr * per;
  int nblk = rem >> 3, mrow = rem & 7;
  int mblk = sr * 8 + mrow;

  size_t arow0 = (size_t)mblk * 128;
  size_t brow0 = (size_t)nblk * 128;
  const int wm = wave >> 1, wn = wave & 1;
  const int lr = lane & 15, grp = lane >> 4;

  // ---- staging: 4 issues/wave/matrix; chunk f -> LDS byte f*16 (linear),
  // global col pre-inverse-swizzled so swizzled reads see the right data ----
  const short* gsa[4]; const short* gsb[4];
  short* lda[4]; short* ldb[4];
  #pragma unroll
  for (int i = 0; i < 4; ++i) {
    int f = i * 256 + wave * 64 + lane;
    int row = f >> 3;
    int colc = (f & 7) ^ (row & 7);          // inverse swizzle (involution)
    gsa[i] = A  + (arow0 + row) * Kd + colc * 8;
    gsb[i] = Bm + (brow0 + row) * Kd + colc * 8;
    lda[i] = &As[(i * 256 + wave * 64) * 8]; // wave-uniform base
    ldb[i] = &Bs[(i * 256 + wave * 64) * 8];
  }

  f32x4 acc[4][4];
  #pragma unroll
  for (int i = 0; i < 4; ++i)
    #pragma unroll
    for (int j = 0; j < 4; ++j) {
      acc[i][j][0] = 0.f; acc[i][j][1] = 0.f; acc[i][j][2] = 0.f; acc[i][j][3] = 0.f;
    }

  // swizzled read offsets (shorts): row*64 + ((kk*64 + grp*16) ^ ((row&7)<<4))/2
  int aoff[4][2], boff[4][2];
  #pragma unroll
  for (int mi = 0; mi < 4; ++mi) {
    int arow = wm * 64 + mi * 16 + lr;
    int brow = wn * 64 + mi * 16 + lr;
    #pragma unroll
    for (int kk = 0; kk < 2; ++kk) {
      int cb = (kk * 64 + grp * 16);
      aoff[mi][kk] = arow * 64 + ((cb ^ ((arow & 7) << 4)) >> 1);
      boff[mi][kk] = brow * 64 + ((cb ^ ((brow & 7) << 4)) >> 1);
    }
  }

  for (int k0 = 0; k0 < Kd; k0 += 64) {
    #pragma unroll
    for (int i = 0; i < 4; ++i) {
      gld16(gsa[i] + k0, lda[i]);
      gld16(gsb[i] + k0, ldb[i]);
    }
    __syncthreads();
    short8 af[4][2], bfr[4][2];
    #pragma unroll
    for (int mi = 0; mi < 4; ++mi)
      #pragma unroll
      for (int kk = 0; kk < 2; ++kk) {
        af[mi][kk]  = *(const short8*)&As[aoff[mi][kk]];
        bfr[mi][kk] = *(const short8*)&Bs[boff[mi][kk]];
      }
    #pragma unroll
    for (int kk = 0; kk < 2; ++kk)
      #pragma unroll
      for (int i = 0; i < 4; ++i)
        #pragma unroll
        for (int j = 0; j < 4; ++j)
          acc[i][j] = __builtin_amdgcn_mfma_f32_16x16x32_bf16(af[i][kk], bfr[j][kk], acc[i][j], 0, 0, 0);
    __syncthreads();
  }

  // C/D layout: col = lane&15, row = (lane>>4)*4 + reg
  int r0 = grp * 4;
  #pragma unroll
  for (int i = 0; i < 4; ++i) {
    size_t grow0 = arow0 + wm * 64 + i * 16 + r0;
    #pragma unroll
    for (int j = 0; j < 4; ++j) {
      size_t gcol = brow0 + wn * 64 + j * 16 + lr;
      float bv = bias[gcol];
      #pragma unroll
      for (int r = 0; r < 4; ++r) {
        float v = acc[i][j][r] + bv;
        size_t off = (grow0 + r) * (size_t)N + gcol;
        if (OUT_BF16) ((short*)C)[off] = f2bf(v);
        else          ((float*)C)[off] = v;
      }
    }
  }
}

// ---------------- MFMA local 7x7 attention ----------------
#define HALO_V 232
#define PROW 168

__global__ __launch_bounds__(256, 3) void attn_mfma(
    const short* __restrict__ qkv, const float* __restrict__ rel_bias,
    short* __restrict__ attn_out)
{
  __shared__ __align__(16) short kvbuf[HALO_V * 64];     // 29696 B (K, then V^T)
  __shared__ __align__(16) short pbuf[4 * 16 * PROW];    // 21504 B
  __shared__ float sbias[49];

  const int tid = threadIdx.x;
  const int wave = tid >> 6, lane = tid & 63;
  const int ht = blockIdx.x >> 2, wt = blockIdx.x & 3;
  const int head = blockIdx.y % 12, b = blockIdx.y / 12;
  const int r0 = ht * 4, c0 = wt * 16;
  const int grp = lane >> 4;
  const int q   = lane & 15;
  const int grp4 = grp * 4, grp8 = grp * 8;
  const int Sw = (22 * wave) & ~7;

  if (tid < 49) sbias[tid] = rel_bias[head * 49 + tid];

  #pragma unroll
  for (int it = 0; it < 8; ++it) {
    int idx = it * 256 + tid;
    if (idx < HALO_V * 8) {
      int vec = idx >> 3, c = idx & 7;
      int hr = vec / 22, hc = vec - hr * 22;
      int gh = r0 - 3 + hr, gw = c0 - 3 + hc;
      short8 val = {};
      if (vec < 220 && (unsigned)gh < 56u && (unsigned)gw < 56u)
        val = *(const short8*)(qkv + ((size_t)((b * 56 + gh) * 56 + gw)) * 2304
                               + 768 + head * 64 + c * 8);
      *(short8*)&kvbuf[vec * 64 + ((c ^ (vec & 7))) * 8] = val;
    }
  }

  const int qrow = r0 + wave;
  const int qcol = min(c0 + q, 55);
  const short* qp = qkv + ((size_t)((b * 56 + qrow) * 56 + qcol)) * 2304 + head * 64;
  short8 qf0 = *(const short8*)(qp + grp8);
  short8 qf1 = *(const short8*)(qp + 32 + grp8);

  __syncthreads();

  f32x4 accs[10];
  #pragma unroll
  for (int kt = 0; kt < 10; ++kt) {
    accs[kt][0] = 0.f; accs[kt][1] = 0.f; accs[kt][2] = 0.f; accs[kt][3] = 0.f;
  }
  #pragma unroll
  for (int kt = 0; kt < 10; ++kt) {
    int vec = Sw + kt * 16 + q;
    int sw = vec & 7;
    short8 k0 = *(const short8*)&kvbuf[vec * 64 + ((grp ^ sw)) * 8];
    short8 k1 = *(const short8*)&kvbuf[vec * 64 + (((grp + 4) ^ sw)) * 8];
    accs[kt] = __builtin_amdgcn_mfma_f32_16x16x32_bf16(k0, qf0, accs[kt], 0, 0, 0);
    accs[kt] = __builtin_amdgcn_mfma_f32_16x16x32_bf16(k1, qf1, accs[kt], 0, 0, 0);
  }

  __syncthreads();

  if (tid < HALO_V) {
    int vec = tid;
    int hr = vec / 22, hc = vec - hr * 22;
    int gh = r0 - 3 + hr, gw = c0 - 3 + hc;
    bool v = (vec < 220) && ((unsigned)gh < 56u) && ((unsigned)gw < 56u);
    int ghc = v ? gh : 0, gwc = v ? gw : 0;
    const short* vp = qkv + ((size_t)((b * 56 + ghc) * 56 + gwc)) * 2304
                      + 1536 + head * 64;
    #pragma unroll
    for (int c = 0; c < 8; ++c) {
      short8 val = {};
      if (v) val = *(const short8*)(vp + c * 8);
      #pragma unroll
      for (int j = 0; j < 8; ++j)
        kvbuf[(c * 8 + j) * HALO_V + vec] = val[j];
    }
  }

  float sv[10][4];
  float mx = -1e30f;
  #pragma unroll
  for (int kt = 0; kt < 10; ++kt) {
    #pragma unroll
    for (int r = 0; r < 4; ++r) {
      int i22 = Sw + kt * 16 + grp4 + r;
      int hr = i22 / 22, hc = i22 - hr * 22;
      int dr = hr - wave, dc = hc - q;
      int kh = r0 - 3 + hr, kw = c0 - 3 + hc;
      bool valid = ((unsigned)dr < 7u) && ((unsigned)dc < 7u) &&
                   ((unsigned)kh < 56u) && ((unsigned)kw < 56u);
      int o = valid ? (dr * 7 + dc) : 0;
      float s = accs[kt][r] * 0.125f + sbias[o];
      s = valid ? s : -1e30f;
      sv[kt][r] = s;
      mx = fmaxf(mx, s);
    }
  }
  mx = fmaxf(mx, __shfl_xor(mx, 16));
  mx = fmaxf(mx, __shfl_xor(mx, 32));
  float sum = 0.f;
  #pragma unroll
  for (int kt = 0; kt < 10; ++kt)
    #pragma unroll
    for (int r = 0; r < 4; ++r) {
      float e = __expf(sv[kt][r] - mx);
      sv[kt][r] = e;
      sum += e;
    }
  sum += __shfl_xor(sum, 16);
  sum += __shfl_xor(sum, 32);
  float inv = 1.0f / sum;

  short* pb = pbuf + wave * 16 * PROW;
  #pragma unroll
  for (int kt = 0; kt < 10; ++kt) {
    s16x4 pk;
    #pragma unroll
    for (int r = 0; r < 4; ++r) pk[r] = f2bf(sv[kt][r] * inv);
    *(s16x4*)&pb[q * PROW + kt * 16 + grp4] = pk;
  }

  __syncthreads();

  f32x4 acco[4];
  #pragma unroll
  for (int dt = 0; dt < 4; ++dt) {
    acco[dt][0] = 0.f; acco[dt][1] = 0.f; acco[dt][2] = 0.f; acco[dt][3] = 0.f;
  }
  #pragma unroll
  for (int km = 0; km < 5; ++km) {
    short8 pf = *(const short8*)&pb[q * PROW + km * 32 + grp8];
    #pragma unroll
    for (int dt = 0; dt < 4; ++dt) {
      short8 vf = *(const short8*)&kvbuf[(dt * 16 + q) * HALO_V + Sw + km * 32 + grp8];
      acco[dt] = __builtin_amdgcn_mfma_f32_16x16x32_bf16(pf, vf, acco[dt], 0, 0, 0);
    }
  }

  #pragma unroll
  for (int dt = 0; dt < 4; ++dt) {
    #pragma unroll
    for (int r = 0; r < 4; ++r) {
      int qc = c0 + grp4 + r;
      if (qc < 56) {
        size_t off = ((size_t)((b * 56 + qrow) * 56 + qc)) * 768
                     + head * 64 + dt * 16 + q;
        attn_out[off] = f2bf(acco[dt][r]);
      }
    }
  }
}

// ---------------- launch ----------------
extern "C" void kernel_launch(void* const* d_in, const int* in_sizes, int n_in,
                              void* d_out, int out_size, void* d_ws, size_t ws_size,
                              hipStream_t stream)
{
  const float* x      = (const float*)d_in[0];
  const float* qkv_w  = (const float*)d_in[1];
  const float* qkv_b  = (const float*)d_in[2];
  const float* rel_b  = (const float*)d_in[3];
  const float* proj_w = (const float*)d_in[4];
  const float* proj_b = (const float*)d_in[5];

  char* ws = (char*)d_ws;
  short* x_bf    = (short*)(ws);
  short* attn_bf = (short*)(ws);                 // reuse (x dead after qkv GEMM)
  short* qw_bf   = (short*)(ws + 77070336);
  short* pw_bf   = (short*)(ws + 80609280);
  short* qkv_bf  = (short*)(ws + 81788928);

  cast_f32_bf16<<<2048, 256, 0, stream>>>(x, x_bf, 38535168 / 8);
  cast_f32_bf16<<<864, 256, 0, stream>>>(qkv_w, qw_bf, 1769472 / 8);
  cast_f32_bf16<<<288, 256, 0, stream>>>(proj_w, pw_bf, 589824 / 8);

  // qkv = x @ qkv_w^T + qkv_b   (M=50176, N=2304, K=768)
  gemm_bt<1><<<392 * 18, 256, 0, stream>>>(x_bf, qw_bf, qkv_b, (void*)qkv_bf,
                                           50176, 2304, 768, 18);

  // local attention -> attn_bf [50176 x 768]
  attn_mfma<<<dim3(56, 192), 256, 0, stream>>>(qkv_bf, rel_b, attn_bf);

  // out = attn @ proj_w^T + proj_b  (M=50176, N=768, K=768), fp32 out
  gemm_bt<0><<<392 * 6, 256, 0, stream>>>(attn_bf, pw_bf, proj_b, d_out,
                                          50176, 768, 768, 6);
}

// Round 4
// 457.937 us; speedup vs baseline: 2.1275x; 1.1576x over previous
//
#include <hip/hip_runtime.h>
#include <hip/hip_bf16.h>

typedef __attribute__((ext_vector_type(8))) short short8;
typedef __attribute__((ext_vector_type(4))) short s16x4;
typedef __attribute__((ext_vector_type(4))) float f32x4;

#define AS1 __attribute__((address_space(1)))
#define AS3 __attribute__((address_space(3)))

__device__ __forceinline__ void gld16(const short* g, short* l) {
  __builtin_amdgcn_global_load_lds((const AS1 void*)g, (AS3 void*)l, 16, 0, 0);
}

__device__ __forceinline__ float bf2f(short x) {
  return __uint_as_float(((unsigned)(unsigned short)x) << 16);
}
__device__ __forceinline__ short f2bf(float f) {
  unsigned u = __float_as_uint(f);
  return (short)((u + 0x7fffu + ((u >> 16) & 1u)) >> 16);  // RNE
}
__device__ __forceinline__ short f2bfn(float f) {
  __hip_bfloat16 h = __float2bfloat16(f);
  return *reinterpret_cast<short*>(&h);
}

// ---------------- cast fp32 -> bf16, 8 elems/thread ----------------
__global__ void cast_f32_bf16(const float* __restrict__ src, short* __restrict__ dst, int n8) {
  int stride = gridDim.x * blockDim.x;
  for (int i = blockIdx.x * blockDim.x + threadIdx.x; i < n8; i += stride) {
    const float4* s = (const float4*)(src + (size_t)i * 8);
    float4 a = s[0], b = s[1];
    short8 o;
    o[0] = f2bf(a.x); o[1] = f2bf(a.y); o[2] = f2bf(a.z); o[3] = f2bf(a.w);
    o[4] = f2bf(b.x); o[5] = f2bf(b.y); o[6] = f2bf(b.z); o[7] = f2bf(b.w);
    *(short8*)(dst + (size_t)i * 8) = o;
  }
}

// ---------------- bf16 GEMM, C[M,N] = A[M,K] * B[N,K]^T + bias ----------------
// 128x128 tile, BK=64, T2 XOR-swizzled LDS, T1 XCD-chunk raster. (unchanged)
template<int OUT_BF16>
__global__ __launch_bounds__(256, 2) void gemm_bt(
    const short* __restrict__ A, const short* __restrict__ Bm,
    const float* __restrict__ bias, void* __restrict__ C,
    int M, int N, int Kd, int NB)
{
  __shared__ short As[128 * 64];
  __shared__ short Bs[128 * 64];
  const int tid = threadIdx.x;
  const int wave = tid >> 6, lane = tid & 63;

  int nwg = gridDim.x;
  int chunk = nwg >> 3;
  int bid = blockIdx.x;
  int nb2 = (bid & 7) * chunk + (bid >> 3);
  int per = NB << 3;
  int sr = nb2 / per, rem = nb2 - sr * per;
  int nblk = rem >> 3, mrow = rem & 7;
  int mblk = sr * 8 + mrow;

  size_t arow0 = (size_t)mblk * 128;
  size_t brow0 = (size_t)nblk * 128;
  const int wm = wave >> 1, wn = wave & 1;
  const int lr = lane & 15, grp = lane >> 4;

  const short* gsa[4]; const short* gsb[4];
  short* lda[4]; short* ldb[4];
  #pragma unroll
  for (int i = 0; i < 4; ++i) {
    int f = i * 256 + wave * 64 + lane;
    int row = f >> 3;
    int colc = (f & 7) ^ (row & 7);
    gsa[i] = A  + (arow0 + row) * Kd + colc * 8;
    gsb[i] = Bm + (brow0 + row) * Kd + colc * 8;
    lda[i] = &As[(i * 256 + wave * 64) * 8];
    ldb[i] = &Bs[(i * 256 + wave * 64) * 8];
  }

  f32x4 acc[4][4];
  #pragma unroll
  for (int i = 0; i < 4; ++i)
    #pragma unroll
    for (int j = 0; j < 4; ++j) {
      acc[i][j][0] = 0.f; acc[i][j][1] = 0.f; acc[i][j][2] = 0.f; acc[i][j][3] = 0.f;
    }

  int aoff[4][2], boff[4][2];
  #pragma unroll
  for (int mi = 0; mi < 4; ++mi) {
    int arow = wm * 64 + mi * 16 + lr;
    int brow = wn * 64 + mi * 16 + lr;
    #pragma unroll
    for (int kk = 0; kk < 2; ++kk) {
      int cb = (kk * 64 + grp * 16);
      aoff[mi][kk] = arow * 64 + ((cb ^ ((arow & 7) << 4)) >> 1);
      boff[mi][kk] = brow * 64 + ((cb ^ ((brow & 7) << 4)) >> 1);
    }
  }

  for (int k0 = 0; k0 < Kd; k0 += 64) {
    #pragma unroll
    for (int i = 0; i < 4; ++i) {
      gld16(gsa[i] + k0, lda[i]);
      gld16(gsb[i] + k0, ldb[i]);
    }
    __syncthreads();
    short8 af[4][2], bfr[4][2];
    #pragma unroll
    for (int mi = 0; mi < 4; ++mi)
      #pragma unroll
      for (int kk = 0; kk < 2; ++kk) {
        af[mi][kk]  = *(const short8*)&As[aoff[mi][kk]];
        bfr[mi][kk] = *(const short8*)&Bs[boff[mi][kk]];
      }
    #pragma unroll
    for (int kk = 0; kk < 2; ++kk)
      #pragma unroll
      for (int i = 0; i < 4; ++i)
        #pragma unroll
        for (int j = 0; j < 4; ++j)
          acc[i][j] = __builtin_amdgcn_mfma_f32_16x16x32_bf16(af[i][kk], bfr[j][kk], acc[i][j], 0, 0, 0);
    __syncthreads();
  }

  int r0 = grp * 4;
  #pragma unroll
  for (int i = 0; i < 4; ++i) {
    size_t grow0 = arow0 + wm * 64 + i * 16 + r0;
    #pragma unroll
    for (int j = 0; j < 4; ++j) {
      size_t gcol = brow0 + wn * 64 + j * 16 + lr;
      float bv = bias[gcol];
      #pragma unroll
      for (int r = 0; r < 4; ++r) {
        float v = acc[i][j][r] + bv;
        size_t off = (grow0 + r) * (size_t)N + gcol;
        if (OUT_BF16) ((short*)C)[off] = f2bf(v);
        else          ((float*)C)[off] = v;
      }
    }
  }
}

// ---------------- mask/bias index table: [tile 56][wave 4][lane 64][48 bytes] ----------------
__global__ void build_idx(unsigned char* __restrict__ idxt) {
  int tile = blockIdx.x;
  int ht = tile >> 2, wt = tile & 3;
  int tid = threadIdx.x;
  int wave = tid >> 6, lane = tid & 63;
  int grp = lane >> 4, q = lane & 15;
  int Sw = (22 * wave) & ~7;
  unsigned w[12];
  #pragma unroll
  for (int i = 0; i < 12; ++i) w[i] = 0x31313131u;   // 49 = sentinel
  #pragma unroll
  for (int kt = 0; kt < 10; ++kt) {
    unsigned wd = 0;
    #pragma unroll
    for (int r = 0; r < 4; ++r) {
      int i22 = Sw + kt * 16 + grp * 4 + r;
      int hr = i22 / 22, hc = i22 - hr * 22;
      int dr = hr - wave, dc = hc - q;
      int kh = ht * 4 - 3 + hr, kw = wt * 16 - 3 + hc;
      bool valid = ((unsigned)dr < 7u) && ((unsigned)dc < 7u) &&
                   ((unsigned)kh < 56u) && ((unsigned)kw < 56u);
      unsigned o = valid ? (unsigned)(dr * 7 + dc) : 49u;
      wd |= o << (r * 8);
    }
    w[kt] = wd;
  }
  uint4* dst = (uint4*)(idxt + (((size_t)tile * 4 + wave) * 64 + lane) * 48);
  dst[0] = make_uint4(w[0], w[1], w[2], w[3]);
  dst[1] = make_uint4(w[4], w[5], w[6], w[7]);
  dst[2] = make_uint4(w[8], w[9], w[10], w[11]);
}

// ---------------- MFMA local 7x7 attention ----------------
#define HALO_V 232
#define PROW 168

__global__ __launch_bounds__(256, 3) void attn_mfma(
    const short* __restrict__ qkv, const float* __restrict__ rel_bias,
    const unsigned char* __restrict__ idxt, const short* __restrict__ zp,
    short* __restrict__ attn_out)
{
  __shared__ __align__(16) short kvbuf[HALO_V * 64];   // K [232][64] -> V^T [64][232]
  __shared__ __align__(16) short pbuf[4 * 16 * PROW];  // 21504 B
  __shared__ float sbias[52];

  const int tid = threadIdx.x;
  const int wave = tid >> 6, lane = tid & 63;
  const int tile = blockIdx.x;
  const int ht = tile >> 2, wt = tile & 3;
  const int head = blockIdx.y % 12, b = blockIdx.y / 12;
  const int r0 = ht * 4, c0 = wt * 16;
  const int grp = lane >> 4, q = lane & 15;
  const int grp4 = grp * 4, grp8 = grp * 8;
  const int Sw = (22 * wave) & ~7;

  if (tid < 50) sbias[tid] = (tid < 49) ? rel_bias[head * 49 + tid] : -1e30f;

  // mask/bias index words (prefetch early; word kt holds bytes r=0..3)
  const uint4* ip = (const uint4*)(idxt + (((size_t)tile * 4 + wave) * 64 + lane) * 48);
  uint4 iw0 = ip[0], iw1 = ip[1], iw2 = ip[2];
  unsigned idxw[10] = {iw0.x, iw0.y, iw0.z, iw0.w, iw1.x, iw1.y, iw1.z, iw1.w,
                       iw2.x, iw2.y};

  // Q fragments
  const int qrow = r0 + wave;
  const int qcol = min(c0 + q, 55);
  const short* qp = qkv + ((size_t)((b * 56 + qrow) * 56 + qcol)) * 2304 + head * 64;
  short8 qf0 = *(const short8*)(qp + grp8);
  short8 qf1 = *(const short8*)(qp + 32 + grp8);

  // ---- K stage via global_load_lds, inverse-pre-swizzled source ----
  #pragma unroll
  for (int it = 0; it < 8; ++it) {
    int f = it * 256 + tid;
    if (f < HALO_V * 8) {                      // wave-uniform (tail = wave 0 only)
      int row = f >> 3, cc = f & 7;
      int hr = row / 22, hc = row - hr * 22;
      int gh = r0 - 3 + hr, gw = c0 - 3 + hc;
      bool ok = (row < 220) && ((unsigned)gh < 56u) && ((unsigned)gw < 56u);
      const short* src = ok
        ? qkv + ((size_t)((b * 56 + gh) * 56 + gw)) * 2304 + 768 + head * 64
              + ((cc ^ (row & 7)) * 8)
        : zp;
      gld16(src, &kvbuf[(it * 256 + wave * 64) * 8]);
    }
  }

  __syncthreads();   // K staged

  // ---- issue V loads early (arrive during QK) ----
  short8 va[4], vb[4];
  int vq = 0, dcc = 0;
  const bool vact = (tid < HALO_V);
  if (vact) {
    vq = tid % 58; dcc = tid / 58;
    #pragma unroll
    for (int rr = 0; rr < 4; ++rr) {
      int vec = vq * 4 + rr;
      int hr = vec / 22, hc = vec - hr * 22;
      int gh = r0 - 3 + hr, gw = c0 - 3 + hc;
      bool ok = (vec < 220) && ((unsigned)gh < 56u) && ((unsigned)gw < 56u);
      const short8* vp = ok
        ? (const short8*)(qkv + ((size_t)((b * 56 + gh) * 56 + gw)) * 2304
                          + 1536 + head * 64 + dcc * 16)
        : (const short8*)zp;
      va[rr] = vp[0]; vb[rr] = vp[1];
    }
  }

  // ---- QK^T: C[key, q] ----
  f32x4 accs[10];
  #pragma unroll
  for (int kt = 0; kt < 10; ++kt) {
    accs[kt][0] = 0.f; accs[kt][1] = 0.f; accs[kt][2] = 0.f; accs[kt][3] = 0.f;
  }
  #pragma unroll
  for (int kt = 0; kt < 10; ++kt) {
    int vec = Sw + kt * 16 + q;
    int sw = vec & 7;
    short8 k0 = *(const short8*)&kvbuf[vec * 64 + ((grp ^ sw)) * 8];
    short8 k1 = *(const short8*)&kvbuf[vec * 64 + (((grp + 4) ^ sw)) * 8];
    accs[kt] = __builtin_amdgcn_mfma_f32_16x16x32_bf16(k0, qf0, accs[kt], 0, 0, 0);
    accs[kt] = __builtin_amdgcn_mfma_f32_16x16x32_bf16(k1, qf1, accs[kt], 0, 0, 0);
  }

  __syncthreads();   // all QK reads done; kvbuf reusable

  // ---- softmax (in-place in accs): s = acc*0.125 + sbias[idx] ----
  float mx = -1e30f;
  #pragma unroll
  for (int kt = 0; kt < 10; ++kt) {
    #pragma unroll
    for (int r = 0; r < 4; ++r) {
      float bia = sbias[(idxw[kt] >> (r * 8)) & 0xffu];
      float s = fmaf(accs[kt][r], 0.125f, bia);
      accs[kt][r] = s;
      mx = fmaxf(mx, s);
    }
  }
  mx = fmaxf(mx, __shfl_xor(mx, 16));
  mx = fmaxf(mx, __shfl_xor(mx, 32));
  float sum = 0.f;
  #pragma unroll
  for (int kt = 0; kt < 10; ++kt)
    #pragma unroll
    for (int r = 0; r < 4; ++r) {
      float e = __expf(accs[kt][r] - mx);
      accs[kt][r] = e;
      sum += e;
    }
  sum += __shfl_xor(sum, 16);
  sum += __shfl_xor(sum, 32);
  float inv = 1.0f / sum;

  // ---- V transpose write: V^T [d][232] (register 4x16 transpose, b64 writes) ----
  if (vact) {
    #pragma unroll
    for (int dd = 0; dd < 8; ++dd) {
      s16x4 w;
      w[0] = va[0][dd]; w[1] = va[1][dd]; w[2] = va[2][dd]; w[3] = va[3][dd];
      *(s16x4*)&kvbuf[(dcc * 16 + dd) * HALO_V + vq * 4] = w;
    }
    #pragma unroll
    for (int dd = 0; dd < 8; ++dd) {
      s16x4 w;
      w[0] = vb[0][dd]; w[1] = vb[1][dd]; w[2] = vb[2][dd]; w[3] = vb[3][dd];
      *(s16x4*)&kvbuf[(dcc * 16 + 8 + dd) * HALO_V + vq * 4] = w;
    }
  }

  // ---- write P (bf16, UNNORMALIZED) to pbuf[q][key] ----
  short* pb = pbuf + wave * 16 * PROW;
  #pragma unroll
  for (int kt = 0; kt < 10; ++kt) {
    s16x4 pk;
    #pragma unroll
    for (int r = 0; r < 4; ++r) pk[r] = f2bfn(accs[kt][r]);
    *(s16x4*)&pb[q * PROW + kt * 16 + grp4] = pk;
  }

  __syncthreads();   // V^T staged

  // ---- PV ----
  f32x4 acco[4];
  #pragma unroll
  for (int dt = 0; dt < 4; ++dt) {
    acco[dt][0] = 0.f; acco[dt][1] = 0.f; acco[dt][2] = 0.f; acco[dt][3] = 0.f;
  }
  #pragma unroll
  for (int km = 0; km < 5; ++km) {
    short8 pf = *(const short8*)&pb[q * PROW + km * 32 + grp8];
    #pragma unroll
    for (int dt = 0; dt < 4; ++dt) {
      short8 vf = *(const short8*)&kvbuf[(dt * 16 + q) * HALO_V + Sw + km * 32 + grp8];
      acco[dt] = __builtin_amdgcn_mfma_f32_16x16x32_bf16(pf, vf, acco[dt], 0, 0, 0);
    }
  }

  // ---- store with per-row 1/sum (rows are OTHER lanes' queries) ----
  float invr[4];
  #pragma unroll
  for (int r = 0; r < 4; ++r) invr[r] = __shfl(inv, grp4 + r);
  #pragma unroll
  for (int dt = 0; dt < 4; ++dt) {
    #pragma unroll
    for (int r = 0; r < 4; ++r) {
      int qc = c0 + grp4 + r;
      if (qc < 56) {
        size_t off = ((size_t)((b * 56 + qrow) * 56 + qc)) * 768
                     + head * 64 + dt * 16 + q;
        attn_out[off] = f2bfn(acco[dt][r] * invr[r]);
      }
    }
  }
}

// ---------------- launch ----------------
extern "C" void kernel_launch(void* const* d_in, const int* in_sizes, int n_in,
                              void* d_out, int out_size, void* d_ws, size_t ws_size,
                              hipStream_t stream)
{
  const float* x      = (const float*)d_in[0];
  const float* qkv_w  = (const float*)d_in[1];
  const float* qkv_b  = (const float*)d_in[2];
  const float* rel_b  = (const float*)d_in[3];
  const float* proj_w = (const float*)d_in[4];
  const float* proj_b = (const float*)d_in[5];

  char* ws = (char*)d_ws;
  short* x_bf    = (short*)(ws);
  short* attn_bf = (short*)(ws);                 // reuse (x dead after qkv GEMM)
  short* qw_bf   = (short*)(ws + 77070336);
  short* pw_bf   = (short*)(ws + 80609280);
  short* qkv_bf  = (short*)(ws + 81788928);
  unsigned char* idxt = (unsigned char*)(ws + 312999936);  // 688128 B
  short* zp      = (short*)(ws + 313688064);               // 256 B zero page

  hipMemsetAsync(zp, 0, 256, stream);
  build_idx<<<56, 256, 0, stream>>>(idxt);

  cast_f32_bf16<<<2048, 256, 0, stream>>>(x, x_bf, 38535168 / 8);
  cast_f32_bf16<<<864, 256, 0, stream>>>(qkv_w, qw_bf, 1769472 / 8);
  cast_f32_bf16<<<288, 256, 0, stream>>>(proj_w, pw_bf, 589824 / 8);

  // qkv = x @ qkv_w^T + qkv_b   (M=50176, N=2304, K=768)
  gemm_bt<1><<<392 * 18, 256, 0, stream>>>(x_bf, qw_bf, qkv_b, (void*)qkv_bf,
                                           50176, 2304, 768, 18);

  // local attention -> attn_bf [50176 x 768]
  attn_mfma<<<dim3(56, 192), 256, 0, stream>>>(qkv_bf, rel_b, idxt, zp, attn_bf);

  // out = attn @ proj_w^T + proj_b  (M=50176, N=768, K=768), fp32 out
  gemm_bt<0><<<392 * 6, 256, 0, stream>>>(attn_bf, pw_bf, proj_b, d_out,
                                          50176, 768, 768, 6);
}